// Round 8
// baseline (61.249 us; speedup 1.0000x reference)
//
#include <hip/hip_runtime.h>

#define NPTS 512
#define DIM 128
#define MARGIN 0.2f
#define NTHR 512

// ---------------- K0: transpose z[512][128] -> zt4[32][512] (float4-major) ---
// zt4[kk][c] = float4(z[c][4kk .. 4kk+3]).  8 blocks x 512 thr, LDS-tiled.
__global__ __launch_bounds__(512) void transpose_kernel(
    const float* __restrict__ z, float4* __restrict__ zt4)
{
    __shared__ float4 lds[64 * 33];            // 64 rows x 32 kk, pad 33
    const int t = threadIdx.x;
    const int b = blockIdx.x;                  // row group: rows b*64 .. +63
    const float4* z4 = reinterpret_cast<const float4*>(z);

    #pragma unroll
    for (int i = 0; i < 4; ++i) {              // coalesced read of 64 rows
        int f = i * 512 + t;                   // 0..2047 local f4 index
        int row = f >> 5, kk = f & 31;
        lds[row * 33 + kk] = z4[b * 2048 + f];
    }
    __syncthreads();
    #pragma unroll
    for (int i = 0; i < 4; ++i) {              // coalesced write along c
        int w = i * 512 + t;
        int kk = w >> 6, c = w & 63;
        zt4[kk * NPTS + b * 64 + c] = lds[c * 33 + kk];
    }
}

// ---------------- K1: per-anchor distances (streaming) + triplet tail --------
// Block a, thread c: d(a,c) from 32 contiguous float4 wave-loads of zt4;
// anchor row broadcast from 512B LDS. No staging, no barrier in hot loop.
__global__ __launch_bounds__(NTHR, 4) void triplet_partial_kernel(
    const float4* __restrict__ zt4, const float* __restrict__ z,
    const int* __restrict__ labels,
    float* __restrict__ psum, unsigned* __restrict__ pcnt,
    unsigned* __restrict__ pntrip)
{
    __shared__ float4 za4[DIM / 4];            // 512 B anchor row
    __shared__ __align__(16) float pdm[NPTS];  // 2 KB compacted d(a,p)+margin
    __shared__ int wcnt[8];
    __shared__ float red_f[8];
    __shared__ unsigned red_c[8];

    const int t = threadIdx.x;                 // candidate c = t
    const int a = blockIdx.x;
    const int wid = t >> 6, lane = t & 63;

    const int lt = labels[t];
    const int la = labels[a];                  // uniform s_load

    if (t < DIM / 4)
        za4[t] = reinterpret_cast<const float4*>(z)[(size_t)a * (DIM / 4) + t];
    __syncthreads();

    // ---- streaming distance: 32 contiguous wave-loads, deep MLP ----
    float4 acc4 = make_float4(0.f, 0.f, 0.f, 0.f);
    #pragma unroll
    for (int kk = 0; kk < DIM / 4; ++kk) {
        float4 v = zt4[kk * NPTS + t];         // 64 lanes x 16B contiguous
        float4 w = za4[kk];                    // LDS broadcast (uniform addr)
        float d0 = w.x - v.x, d1 = w.y - v.y, d2 = w.z - v.z, d3 = w.w - v.w;
        acc4.x += d0 * d0; acc4.y += d1 * d1;
        acc4.z += d2 * d2; acc4.w += d3 * d3;
    }
    const float d = sqrtf((acc4.x + acc4.y) + (acc4.z + acc4.w));

    // ---- compact positives (deterministic order); d stays in-register ----
    const bool pred = (lt == la) && (t != a);
    const unsigned long long m = __ballot(pred);
    if (lane == 0) wcnt[wid] = (int)__popcll(m);
    __syncthreads();

    unsigned base = 0, np = 0;
    #pragma unroll
    for (int w = 0; w < 8; ++w) {
        unsigned cw = (unsigned)wcnt[w];
        if (w < wid) base += cw;
        np += cw;
    }
    const unsigned npad = (np + 3u) & ~3u;
    if (pred)
        pdm[base + __popcll(m & ((1ull << lane) - 1ull))] = d + MARGIN;
    if ((unsigned)t >= np && (unsigned)t < npad)
        pdm[t] = -1e30f;                       // padding never fires relu
    __syncthreads();

    // ---- accumulate: thread t = negative candidate t ----
    float sum = 0.f;
    unsigned cnt = 0;
    if (lt != la) {
        const float si = d;
        const float4* p4 = reinterpret_cast<const float4*>(pdm);
        const int n4 = (int)(npad >> 2);       // block-uniform, ~2-6 iters
        for (int p = 0; p < n4; ++p) {
            float4 qv = p4[p];                 // LDS broadcast
            float v0 = qv.x - si, v1 = qv.y - si, v2 = qv.z - si, v3 = qv.w - si;
            if (v0 > 0.f) { sum += v0; ++cnt; }
            if (v1 > 0.f) { sum += v1; ++cnt; }
            if (v2 > 0.f) { sum += v2; ++cnt; }
            if (v3 > 0.f) { sum += v3; ++cnt; }
        }
    }

    // ---- block reduction ----
    #pragma unroll
    for (int off = 32; off > 0; off >>= 1) {
        sum += __shfl_down(sum, off, 64);
        cnt += __shfl_down(cnt, off, 64);
    }
    if (lane == 0) { red_f[wid] = sum; red_c[wid] = cnt; }
    __syncthreads();
    if (t == 0) {
        float S = 0.f;
        unsigned C = 0;
        #pragma unroll
        for (int w = 0; w < 8; ++w) { S += red_f[w]; C += red_c[w]; }
        psum[a] = S;
        pcnt[a] = C;
        pntrip[a] = np * (unsigned)(NPTS - 1 - np);
    }
}

// ---------------- K2: deterministic reduction of 512 per-anchor partials ----
__global__ __launch_bounds__(512) void triplet_final_kernel(
    const float* __restrict__ psum, const unsigned* __restrict__ pcnt,
    const unsigned* __restrict__ pntrip, float* __restrict__ out)
{
    __shared__ float rf[8];
    __shared__ unsigned rc[8], rn[8];

    const int t = threadIdx.x;
    float s = psum[t];
    unsigned c = pcnt[t];
    unsigned nt = pntrip[t];

    #pragma unroll
    for (int off = 32; off > 0; off >>= 1) {
        s  += __shfl_down(s,  off, 64);
        c  += __shfl_down(c,  off, 64);
        nt += __shfl_down(nt, off, 64);
    }
    const int wid = t >> 6, lane = t & 63;
    if (lane == 0) { rf[wid] = s; rc[wid] = c; rn[wid] = nt; }
    __syncthreads();
    if (t == 0) {
        double S = 0.0;
        unsigned C = 0, NT = 0;
        #pragma unroll
        for (int w = 0; w < 8; ++w) { S += (double)rf[w]; C += rc[w]; NT += rn[w]; }
        out[0] = (float)(S / (double)NT);
        out[1] = (float)C;
    }
}

extern "C" void kernel_launch(void* const* d_in, const int* in_sizes, int n_in,
                              void* d_out, int out_size, void* d_ws, size_t ws_size,
                              hipStream_t stream) {
    const float* z = (const float*)d_in[0];
    const int* labels = (const int*)d_in[1];
    float* out = (float*)d_out;

    float4* zt4 = (float4*)d_ws;                                 // 256 KB
    float* psum = (float*)((char*)d_ws + 256 * 1024);
    unsigned* pcnt = (unsigned*)((char*)d_ws + 256 * 1024 + NPTS * 4);
    unsigned* pntrip = (unsigned*)((char*)d_ws + 256 * 1024 + NPTS * 8);

    transpose_kernel<<<8, 512, 0, stream>>>(z, zt4);
    triplet_partial_kernel<<<NPTS, NTHR, 0, stream>>>(zt4, z, labels,
                                                      psum, pcnt, pntrip);
    triplet_final_kernel<<<1, NPTS, 0, stream>>>(psum, pcnt, pntrip, out);
}

// Round 10
// 18.063 us; speedup vs baseline: 3.3908x; 3.3908x over previous
//
#include <hip/hip_runtime.h>

#define NPTS 512
#define DIM 128
#define MARGIN 0.2f
#define ATILE 2
#define NBLK (NPTS / ATILE)     // 256 blocks = 1 per CU
#define TROWS 128               // rows per stage tile
#define NTILE (NPTS / TROWS)    // 4 tiles
#define NTHR 512

// Async global->LDS DMA, 16B/lane. LDS dest = wave-uniform base + lane*16
// (linear); swizzle applied by permuting the per-lane SOURCE address and
// mirroring it on the LDS read (both-sides rule; validated in R5).
__device__ __forceinline__ void gload_lds16(const float4* src, float4* dst) {
    __builtin_amdgcn_global_load_lds(
        (const __attribute__((address_space(1))) void*)src,
        (__attribute__((address_space(3))) void*)dst, 16, 0, 0);
}

// R4's proven shape (ATILE=2, 256 blocks, 512 thr, two-kernel) with the
// distance phase rebuilt: dbuf DMA staging + in-wave k-split reduce.
__global__ __launch_bounds__(NTHR) void triplet_partial_kernel(
    const float* __restrict__ z, const int* __restrict__ labels,
    float* __restrict__ psum, unsigned* __restrict__ pcnt,
    unsigned* __restrict__ pntrip)
{
    __shared__ float4 stage[2][TROWS * 32];              // 128 KB double buffer
    __shared__ float drow[ATILE][NPTS];                  // 4 KB
    __shared__ __align__(16) float pdm[ATILE][NPTS];     // 4 KB
    __shared__ int wcnt[ATILE][8];
    __shared__ float red_f[8];
    __shared__ unsigned red_c[8];

    const int t = threadIdx.x;
    const int b = blockIdx.x;
    const int a0 = b * ATILE;
    const int wid = t >> 6, lane = t & 63;
    const int r = t >> 2;            // row within tile (0..127); lanes l,l^1,l^2,l^3 share r
    const int q = t & 3;             // k-quarter
    const int rx = r & 7;
    const int lane5 = lane & 31, lh = lane >> 5;

    const float4* zg = reinterpret_cast<const float4*>(z);

    // Early independent loads.
    const int lt = labels[t];
    int la[ATILE];
    #pragma unroll
    for (int i = 0; i < ATILE; ++i) la[i] = labels[a0 + i];

    float4 za[ATILE][8];             // anchor rows, own k-quarter (chunks q*8+kk)
    #pragma unroll
    for (int i = 0; i < ATILE; ++i)
        #pragma unroll
        for (int kk = 0; kk < 8; ++kk)
            za[i][kk] = zg[(size_t)(a0 + i) * 32 + q * 8 + kk];

    // Prologue: DMA tile 0 (source pre-swizzled, LDS linear).
    #pragma unroll
    for (int p = 0; p < 8; ++p) {
        int row = (wid << 4) + (p << 1) + lh;
        int srcu = row * 32 + (lane5 ^ (row & 7));
        gload_lds16(zg + srcu, &stage[0][(wid << 9) + (p << 6)]);
    }
    __syncthreads();                 // vmcnt drained -> buf0 ready

    for (int T = 0; T < NTILE; ++T) {
        const int cur = T & 1;
        if (T + 1 < NTILE) {         // issue next tile's DMA before computing
            #pragma unroll
            for (int p = 0; p < 8; ++p) {
                int row = (wid << 4) + (p << 1) + lh;
                int srcu = ((T + 1) * TROWS + row) * 32 + (lane5 ^ (row & 7));
                gload_lds16(zg + srcu, &stage[cur ^ 1][(wid << 9) + (p << 6)]);
            }
        }
        float acc0 = 0.f, acc1 = 0.f;
        #pragma unroll
        for (int kk = 0; kk < 8; ++kk) {
            float4 v = stage[cur][r * 32 + ((q * 8 + kk) ^ rx)];
            float4 w0 = za[0][kk], w1 = za[1][kk];
            float d0 = w0.x - v.x, d1 = w0.y - v.y, d2 = w0.z - v.z, d3 = w0.w - v.w;
            acc0 += d0 * d0 + d1 * d1 + d2 * d2 + d3 * d3;
            float e0 = w1.x - v.x, e1 = w1.y - v.y, e2 = w1.z - v.z, e3 = w1.w - v.w;
            acc1 += e0 * e0 + e1 * e1 + e2 * e2 + e3 * e3;
        }
        // in-wave k-quarter reduction (lanes l, l^1, l^2, l^3 share row r)
        acc0 += __shfl_xor(acc0, 1, 64);
        acc0 += __shfl_xor(acc0, 2, 64);
        acc1 += __shfl_xor(acc1, 1, 64);
        acc1 += __shfl_xor(acc1, 2, 64);
        if (q == 0) {
            drow[0][T * TROWS + r] = sqrtf(acc0);
            drow[1][T * TROWS + r] = sqrtf(acc1);
        }
        __syncthreads();             // one barrier/tile: drains DMA, orders drow/buf
    }

    // ---- compact positives per anchor (R4-verbatim tail) ----
    bool pred[ATILE];
    unsigned long long m[ATILE];
    #pragma unroll
    for (int i = 0; i < ATILE; ++i) {
        pred[i] = (lt == la[i]) && (t != a0 + i);
        m[i] = __ballot(pred[i]);
        if (lane == 0) wcnt[i][wid] = (int)__popcll(m[i]);
    }
    __syncthreads();

    unsigned np[ATILE], npad[ATILE];
    #pragma unroll
    for (int i = 0; i < ATILE; ++i) {
        unsigned base = 0, n = 0;
        #pragma unroll
        for (int w = 0; w < 8; ++w) {
            unsigned c = (unsigned)wcnt[i][w];
            if (w < wid) base += c;
            n += c;
        }
        np[i] = n;
        npad[i] = (n + 3u) & ~3u;
        if (pred[i])
            pdm[i][base + __popcll(m[i] & ((1ull << lane) - 1ull))] = drow[i][t] + MARGIN;
        if ((unsigned)t >= n && (unsigned)t < npad[i])
            pdm[i][t] = -1e30f;                          // padding never fires relu
    }
    __syncthreads();

    // ---- accumulate: thread t = negative candidate t ----
    float sum = 0.f;
    unsigned cnt = 0;
    #pragma unroll
    for (int i = 0; i < ATILE; ++i) {
        if (lt != la[i]) {
            const float si = drow[i][t];
            const float4* p4 = reinterpret_cast<const float4*>(pdm[i]);
            const int n4 = (int)(npad[i] >> 2);
            for (int p = 0; p < n4; ++p) {
                float4 qv = p4[p];                       // LDS broadcast
                float v0 = qv.x - si, v1 = qv.y - si, v2 = qv.z - si, v3 = qv.w - si;
                if (v0 > 0.f) { sum += v0; ++cnt; }
                if (v1 > 0.f) { sum += v1; ++cnt; }
                if (v2 > 0.f) { sum += v2; ++cnt; }
                if (v3 > 0.f) { sum += v3; ++cnt; }
            }
        }
    }

    // ---- block reduction ----
    #pragma unroll
    for (int off = 32; off > 0; off >>= 1) {
        sum += __shfl_down(sum, off, 64);
        cnt += __shfl_down(cnt, off, 64);
    }
    if (lane == 0) { red_f[wid] = sum; red_c[wid] = cnt; }
    __syncthreads();
    if (t == 0) {
        float S = 0.f;
        unsigned C = 0;
        #pragma unroll
        for (int w = 0; w < 8; ++w) { S += red_f[w]; C += red_c[w]; }
        unsigned NT = 0;
        #pragma unroll
        for (int i = 0; i < ATILE; ++i) NT += np[i] * (unsigned)(NPTS - 1 - np[i]);
        psum[b] = S;
        pcnt[b] = C;
        pntrip[b] = NT;
    }
}

// Deterministic reduction of the 256 per-block partials (R4-verbatim).
__global__ __launch_bounds__(256) void triplet_final_kernel(
    const float* __restrict__ psum, const unsigned* __restrict__ pcnt,
    const unsigned* __restrict__ pntrip, float* __restrict__ out)
{
    __shared__ float rf[4];
    __shared__ unsigned rc[4], rn[4];

    const int t = threadIdx.x;
    float s = psum[t];
    unsigned c = pcnt[t];
    unsigned nt = pntrip[t];

    #pragma unroll
    for (int off = 32; off > 0; off >>= 1) {
        s  += __shfl_down(s,  off, 64);
        c  += __shfl_down(c,  off, 64);
        nt += __shfl_down(nt, off, 64);
    }
    const int wid = t >> 6, lane = t & 63;
    if (lane == 0) { rf[wid] = s; rc[wid] = c; rn[wid] = nt; }
    __syncthreads();
    if (t == 0) {
        double S = 0.0;
        unsigned C = 0, NT = 0;
        #pragma unroll
        for (int w = 0; w < 4; ++w) { S += (double)rf[w]; C += rc[w]; NT += rn[w]; }
        out[0] = (float)(S / (double)NT);
        out[1] = (float)C;
    }
}

extern "C" void kernel_launch(void* const* d_in, const int* in_sizes, int n_in,
                              void* d_out, int out_size, void* d_ws, size_t ws_size,
                              hipStream_t stream) {
    const float* z = (const float*)d_in[0];
    const int* labels = (const int*)d_in[1];
    float* out = (float*)d_out;

    float* psum = (float*)d_ws;
    unsigned* pcnt = (unsigned*)((char*)d_ws + NBLK * sizeof(float));
    unsigned* pntrip = pcnt + NBLK;

    triplet_partial_kernel<<<NBLK, NTHR, 0, stream>>>(z, labels, psum, pcnt, pntrip);
    triplet_final_kernel<<<1, NBLK, 0, stream>>>(psum, pcnt, pntrip, out);
}

// Round 11
// 15.077 us; speedup vs baseline: 4.0623x; 1.1980x over previous
//
#include <hip/hip_runtime.h>

#define NPTS 512
#define DIM 128
#define MARGIN 0.2f
#define ATILE 2
#define NBLK (NPTS / ATILE)     // 256 blocks = 1 per CU
#define TROWS 256               // rows per LDS stage tile
#define NTILE (NPTS / TROWS)    // 2 tiles
#define NTHR 512

// R4's proven structure with ONE change: TROWS 128 -> 256 (2 tiles, not 4).
// Fewer phase-groups/barriers, deeper staged-load pipelining, full-width sqrt.
__global__ __launch_bounds__(NTHR) void triplet_partial_kernel(
    const float* __restrict__ z, const int* __restrict__ labels,
    float* __restrict__ psum, unsigned* __restrict__ pcnt,
    unsigned* __restrict__ pntrip)
{
    __shared__ float4 stage[TROWS * 32];                 // 128 KB
    __shared__ float part[4][TROWS][ATILE];              // 8 KB
    __shared__ float drow[ATILE][NPTS];                  // 4 KB
    __shared__ __align__(16) float pdm[ATILE][NPTS];     // 4 KB
    __shared__ int wcnt[ATILE][8];
    __shared__ float red_f[8];
    __shared__ unsigned red_c[8];

    const int t = threadIdx.x;
    const int b = blockIdx.x;
    const int a0 = b * ATILE;
    const int wid = t >> 6, lane = t & 63;
    const int q = t >> 7;               // k-quarter (uniform per wave)
    const int r = t & 127;              // base row; thread covers r and r+128

    const float4* zg = reinterpret_cast<const float4*>(z);

    // Anchor rows (own k-quarter) in registers; lane-uniform addr -> 1 txn each.
    float4 za[ATILE][8];
    #pragma unroll
    for (int i = 0; i < ATILE; ++i)
        #pragma unroll
        for (int kk = 0; kk < 8; ++kk)
            za[i][kk] = zg[(size_t)(a0 + i) * 32 + q * 8 + kk];

    // ---- distance phase: 2 staged tiles of 256 rows ----
    for (int T = 0; T < NTILE; ++T) {
        #pragma unroll
        for (int p = 0; p < 16; ++p) {                   // coalesced stage (16 deep)
            int f = p * 512 + t;                         // 0..8191
            int row = f >> 5, chunk = f & 31;
            stage[row * 32 + (chunk ^ (row & 7))] =
                zg[(size_t)(T * TROWS + row) * 32 + chunk];
        }
        __syncthreads();                                 // stage ready; prev part reads done

        #pragma unroll
        for (int rr = 0; rr < 2; ++rr) {                 // rows r and r+128
            const int row = r + rr * 128;
            const int rx = row & 7;
            float acc0 = 0.f, acc1 = 0.f;
            #pragma unroll
            for (int kk = 0; kk < 8; ++kk) {
                float4 v = stage[row * 32 + ((q * 8 + kk) ^ rx)];
                float4 w0 = za[0][kk], w1 = za[1][kk];
                float d0 = w0.x - v.x, d1 = w0.y - v.y, d2 = w0.z - v.z, d3 = w0.w - v.w;
                acc0 += d0 * d0 + d1 * d1 + d2 * d2 + d3 * d3;
                float e0 = w1.x - v.x, e1 = w1.y - v.y, e2 = w1.z - v.z, e3 = w1.w - v.w;
                acc1 += e0 * e0 + e1 * e1 + e2 * e2 + e3 * e3;
            }
            part[q][row][0] = acc0;
            part[q][row][1] = acc1;
        }
        __syncthreads();                                 // part ready; stage reads done

        {                                                // all 512 threads do sqrt
            const int rr = t & 255, ii = t >> 8;
            float s = part[0][rr][ii] + part[1][rr][ii]
                    + part[2][rr][ii] + part[3][rr][ii];
            drow[ii][T * TROWS + rr] = sqrtf(s);
        }
        // next iteration's stage-sync orders part reads vs next part writes
    }
    __syncthreads();                                     // drow complete

    // ---- compact positives per anchor (R4-verbatim tail) ----
    const int lt = labels[t];
    int la[ATILE];
    #pragma unroll
    for (int i = 0; i < ATILE; ++i) la[i] = labels[a0 + i];

    bool pred[ATILE];
    unsigned long long m[ATILE];
    #pragma unroll
    for (int i = 0; i < ATILE; ++i) {
        pred[i] = (lt == la[i]) && (t != a0 + i);
        m[i] = __ballot(pred[i]);
        if (lane == 0) wcnt[i][wid] = (int)__popcll(m[i]);
    }
    __syncthreads();

    unsigned np[ATILE], npad[ATILE];
    #pragma unroll
    for (int i = 0; i < ATILE; ++i) {
        unsigned base = 0, n = 0;
        #pragma unroll
        for (int w = 0; w < 8; ++w) {
            unsigned c = (unsigned)wcnt[i][w];
            if (w < wid) base += c;
            n += c;
        }
        np[i] = n;
        npad[i] = (n + 3u) & ~3u;
        if (pred[i])
            pdm[i][base + __popcll(m[i] & ((1ull << lane) - 1ull))] = drow[i][t] + MARGIN;
        if ((unsigned)t >= n && (unsigned)t < npad[i])
            pdm[i][t] = -1e30f;                          // padding never fires relu
    }
    __syncthreads();

    // ---- accumulate: thread t = negative candidate t ----
    float sum = 0.f;
    unsigned cnt = 0;
    #pragma unroll
    for (int i = 0; i < ATILE; ++i) {
        if (lt != la[i]) {
            const float si = drow[i][t];
            const float4* p4 = reinterpret_cast<const float4*>(pdm[i]);
            const int n4 = (int)(npad[i] >> 2);
            for (int p = 0; p < n4; ++p) {
                float4 qv = p4[p];                       // LDS broadcast
                float v0 = qv.x - si, v1 = qv.y - si, v2 = qv.z - si, v3 = qv.w - si;
                if (v0 > 0.f) { sum += v0; ++cnt; }
                if (v1 > 0.f) { sum += v1; ++cnt; }
                if (v2 > 0.f) { sum += v2; ++cnt; }
                if (v3 > 0.f) { sum += v3; ++cnt; }
            }
        }
    }

    // ---- block reduction ----
    #pragma unroll
    for (int off = 32; off > 0; off >>= 1) {
        sum += __shfl_down(sum, off, 64);
        cnt += __shfl_down(cnt, off, 64);
    }
    if (lane == 0) { red_f[wid] = sum; red_c[wid] = cnt; }
    __syncthreads();
    if (t == 0) {
        float S = 0.f;
        unsigned C = 0;
        #pragma unroll
        for (int w = 0; w < 8; ++w) { S += red_f[w]; C += red_c[w]; }
        unsigned NT = 0;
        #pragma unroll
        for (int i = 0; i < ATILE; ++i) NT += np[i] * (unsigned)(NPTS - 1 - np[i]);
        psum[b] = S;
        pcnt[b] = C;
        pntrip[b] = NT;
    }
}

// Deterministic reduction of the 256 per-block partials (R4-verbatim).
__global__ __launch_bounds__(256) void triplet_final_kernel(
    const float* __restrict__ psum, const unsigned* __restrict__ pcnt,
    const unsigned* __restrict__ pntrip, float* __restrict__ out)
{
    __shared__ float rf[4];
    __shared__ unsigned rc[4], rn[4];

    const int t = threadIdx.x;
    float s = psum[t];
    unsigned c = pcnt[t];
    unsigned nt = pntrip[t];

    #pragma unroll
    for (int off = 32; off > 0; off >>= 1) {
        s  += __shfl_down(s,  off, 64);
        c  += __shfl_down(c,  off, 64);
        nt += __shfl_down(nt, off, 64);
    }
    const int wid = t >> 6, lane = t & 63;
    if (lane == 0) { rf[wid] = s; rc[wid] = c; rn[wid] = nt; }
    __syncthreads();
    if (t == 0) {
        double S = 0.0;
        unsigned C = 0, NT = 0;
        #pragma unroll
        for (int w = 0; w < 4; ++w) { S += (double)rf[w]; C += rc[w]; NT += rn[w]; }
        out[0] = (float)(S / (double)NT);
        out[1] = (float)C;
    }
}

extern "C" void kernel_launch(void* const* d_in, const int* in_sizes, int n_in,
                              void* d_out, int out_size, void* d_ws, size_t ws_size,
                              hipStream_t stream) {
    const float* z = (const float*)d_in[0];
    const int* labels = (const int*)d_in[1];
    float* out = (float*)d_out;

    float* psum = (float*)d_ws;
    unsigned* pcnt = (unsigned*)((char*)d_ws + NBLK * sizeof(float));
    unsigned* pntrip = pcnt + NBLK;

    triplet_partial_kernel<<<NBLK, NTHR, 0, stream>>>(z, labels, psum, pcnt, pntrip);
    triplet_final_kernel<<<1, NBLK, 0, stream>>>(psum, pcnt, pntrip, out);
}